// Round 1
// baseline (108.938 us; speedup 1.0000x reference)
//
#include <hip/hip_runtime.h>

// Problem constants (from reference): B=4, T=512, S=256, V=50257.
#define DIM_B 4
#define DIM_T 512
#define DIM_S 256
#define DIM_V 50257

// One block per output row (b,t). The block:
//   1. zeroes its 50257-float row (float4 vectorized, head/tail for alignment),
//   2. __syncthreads() (implies vmcnt(0) drain -> zeros visible at L2),
//   3. scatter-adds the S=256 source-position probs into vocab bins via atomicAdd.
// Row ownership is exclusive per block -> no cross-block races; duplicate vocab
// indices within the row are handled by the atomics (L2-warm from the zeroing).
__global__ __launch_bounds__(256) void merge_scatter_kernel(
    const float* __restrict__ p_pos,   // [B, T, S]
    const int*   __restrict__ src,     // [B, S]  (int64 narrowed to int32 by harness)
    float*       __restrict__ out)     // [B, T, V]
{
    const int row = blockIdx.x;        // row = b*T + t
    const int b   = row / DIM_T;
    const int tid = threadIdx.x;

    float* __restrict__ row_ptr = out + (size_t)row * DIM_V;

    // ---- zero the row (alignment-safe float4) ----
    const size_t base_elems = (size_t)row * DIM_V;
    const int head = (int)((4 - (base_elems & 3)) & 3);   // scalar elems until 16B aligned
    if (tid < head) row_ptr[tid] = 0.0f;

    const int nrem = DIM_V - head;
    const int nvec = nrem >> 2;
    float4* __restrict__ vp = (float4*)(row_ptr + head);
    const float4 z = make_float4(0.0f, 0.0f, 0.0f, 0.0f);
    #pragma unroll 4
    for (int i = tid; i < nvec; i += 256) {
        vp[i] = z;
    }

    const int tail_start = head + (nvec << 2);
    const int ntail = DIM_V - tail_start;                  // 0..3 elements
    if (tid < ntail) row_ptr[tail_start + tid] = 0.0f;

    __syncthreads();   // zeros drained to L2 before atomics

    // ---- scatter: thread tid handles source position s = tid (S == blockDim) ----
    const int   v_idx = src[b * DIM_S + tid];
    const float val   = p_pos[(size_t)row * DIM_S + tid];
    atomicAdd(&row_ptr[v_idx], val);
}

extern "C" void kernel_launch(void* const* d_in, const int* in_sizes, int n_in,
                              void* d_out, int out_size, void* d_ws, size_t ws_size,
                              hipStream_t stream) {
    const float* p_pos = (const float*)d_in[0];   // [B,T,S]
    // d_in[1] = p_target_vocab — unused by the reference output (shape-only).
    const int*   src   = (const int*)d_in[2];     // [B,S]
    float*       out   = (float*)d_out;           // [B,T,V]

    dim3 grid(DIM_B * DIM_T);   // 2048 blocks, one per output row
    dim3 block(DIM_S);          // 256 threads

    merge_scatter_kernel<<<grid, block, 0, stream>>>(p_pos, src, out);
}